// Round 8
// baseline (6256.879 us; speedup 1.0000x reference)
//
#include <hip/hip_runtime.h>
#include <stdint.h>
#include <stddef.h>

// Problem constants (ESN_58317065945127)
#define B_    128
#define T_    2048
#define D_    128
#define H_    1024
#define O_    32
#define LAST_ 20

// Partition: 8 batch-blocks x 16 col-blocks = 128 worker WGs of 256 threads,
// plus NHEAT_ heater WGs (DPM clock experiment, R12).
#define NB_   8
#define NC_   16
#define RING_ 4
#define TWARM_ 8      // steps [1,TWARM): ring B (sc1) exchange; >=TWARM: ring A only
#define NHEAT_ 128

typedef __bf16 bf16x8 __attribute__((ext_vector_type(8)));
typedef __bf16 bf16x4 __attribute__((ext_vector_type(4)));
typedef float  f32x4  __attribute__((ext_vector_type(4)));
typedef unsigned int u32x4 __attribute__((ext_vector_type(4)));

union Pack8  { unsigned long long u;    bf16x4 v; };
union Pack16 { unsigned long long u[2]; u32x4 d; bf16x8 v; };

__device__ __forceinline__ float tanh_fast(float s) {
    float a = fminf(fmaxf(s, -12.0f), 12.0f);
    float e = __expf(2.0f * a);
    return (e - 1.0f) / (e + 1.0f);
}

// R12: HEATER A/B — CLOCK-THROTTLE HYPOTHESIS TEST.
//
// R11 post-mortem: killing the sc1 DRAM write-through collapsed WRITE_SIZE
// 535->13MB exactly as predicted, yet dur barely moved. Evidence table:
// every exchange mechanism since R6 (LLC-poll / L2-poll / sentinel / no-DRAM)
// paces at ~2.9-3.2us/step. A mechanism-independent pacer. Cycle audit at
// 2.4GHz comes up 2x short (compute+exchange ~1.2-1.5us vs 2.9 measured);
// R0->R6 implies ~0.9us per exchange hop = 2160cy — slower than any cache
// tier. All numbers reconcile if the effective clock is ~1.0-1.2GHz: this
// kernel (6% occupancy, 1% HBM, 10% VALU, waves stalled on vmcnt) is the
// DPM governor's idle-detection worst case.
//
// R12 changes ONE variable: +128 heater WGs (wg >= 128) running dependent
// FMA chains on the idle half of the chip, exiting when all 128 workers
// increment flags[200] (plus 2.9s deadline). Worker path byte-identical to
// R11. Clock theory right -> dur ~3.2-4.5ms. Wrong -> ~6.2-6.9ms and the
// theory dies cleanly (then: latency-floor model, cut serial hops).
__global__ __launch_bounds__(256, 1) void esn_persist(
    const float* __restrict__ x, const float* __restrict__ w_in,
    const float* __restrict__ w_r, __bf16* __restrict__ h_exA,
    __bf16* __restrict__ h_exB, float* __restrict__ hs,
    int* __restrict__ flags)
{
    __shared__ bf16x8 ls[2][16][128];   // 2 bufs x 16 batch-rows x 128 16B chunks = 64 KiB

    const int wg  = (int)blockIdx.x;
    const int tid = (int)threadIdx.x;

    // ---- heater role: saturate VALU to hold DPM clocks up ----
    if (wg >= NB_ * NC_) {
        const unsigned long long hdead =
            __builtin_amdgcn_s_memrealtime() + 290000000ull;   // < worker 3s guard
        float a0 = 1.0f + (float)tid * 1e-6f;
        float a1 = a0 * 1.1f, a2 = a0 * 1.2f, a3 = a0 * 1.3f;
        for (;;) {
            for (int i = 0; i < 2048; ++i) {   // ~8k dependent FMAs per flag check
                a0 = fmaf(a0, 0.99999988f, 1e-7f);
                a1 = fmaf(a1, 0.99999988f, 1e-7f);
                a2 = fmaf(a2, 0.99999988f, 1e-7f);
                a3 = fmaf(a3, 0.99999988f, 1e-7f);
            }
            int d = __hip_atomic_load(flags + 200, __ATOMIC_RELAXED,
                                      __HIP_MEMORY_SCOPE_AGENT);
            if (d >= NB_ * NC_) break;
            if (__builtin_amdgcn_s_memrealtime() > hdead) break;
        }
        if (a0 + a1 + a2 + a3 == 0.123456f && tid == 0) flags[201] = 1;  // keep live
        return;
    }

    const int bb  = wg & (NB_ - 1);  // cohort id (batch block)
    const int cb  = wg >> 3;
    const int wv  = tid >> 6;
    const int ln  = tid & 63;
    const int nn  = ln & 15;   // batch index within tile
    const int q   = ln >> 4;   // quad
    const int b0  = bb * 16;
    const int n0  = cb * 64 + wv * 16;

    // Spin deadline ~3s (anti-hang only; tags make acceptance safe).
    const unsigned long long tdead =
        __builtin_amdgcn_s_memrealtime() + 300000000ull;

    // ---- XCD detection, publish leg ----
    int xcc;
    asm volatile("s_getreg_b32 %0, hwreg(HW_REG_XCC_ID)" : "=s"(xcc));
    const int mytag = 0x5A5A0000 | (xcc & 0xFF);
    if (tid == 0)
        __hip_atomic_store(flags + wg, mytag, __ATOMIC_RELAXED,
                           __HIP_MEMORY_SCOPE_AGENT);

    // ---- one-time: weight fragments into registers (A-operand layout) ----
    bf16x8 win[4];                       // w_in cols, K=128 -> 4 chunks
    #pragma unroll
    for (int c = 0; c < 4; ++c) {
        bf16x8 f;
        #pragma unroll
        for (int j = 0; j < 8; ++j)
            f[j] = (__bf16)w_in[(size_t)(c * 32 + q * 8 + j) * H_ + (n0 + nn)];
        win[c] = f;
    }
    bf16x8 wr[32];                       // w_r cols, K=1024 -> 32 chunks (128 regs)
    #pragma unroll
    for (int kc = 0; kc < 32; ++kc) {
        bf16x8 f;
        #pragma unroll
        for (int j = 0; j < 8; ++j)
            f[j] = (__bf16)w_r[(size_t)(kc * 32 + q * 8 + j) * H_ + (n0 + nn)];
        wr[kc] = f;
    }

    // ---- XCD detection, collect leg: unanimous vote enables ring A ----
    bool votefast;
    {
        int alleq = 0;
        for (;;) {
            int seen = 1; alleq = 1;
            #pragma unroll
            for (int k = 0; k < NC_; ++k) {
                int v = __hip_atomic_load(flags + (bb + 8 * k), __ATOMIC_RELAXED,
                                          __HIP_MEMORY_SCOPE_AGENT);
                seen  &= (int)((v & 0xFFFF0000) == 0x5A5A0000);
                alleq &= (int)(v == mytag);
            }
            if (seen) break;
            __builtin_amdgcn_s_sleep(8);
            if (__builtin_amdgcn_s_memrealtime() > tdead) { alleq = 0; break; }
        }
        votefast = (alleq != 0);
    }

    const float* xrow = x + (size_t)(b0 + nn) * T_ * D_ + q * 8;  // x[b][t][k]
    const size_t hrow = (size_t)(b0 + nn) * H_;

    // sentinel element offset within a ring slot's cohort block:
    // row 15, col (ln>>2)*64 + (ln&3)*16 + 12  (the q=3 word of producer
    // wave (cb'=ln>>2, wv'=ln&3), written by its lane 63). 8B-aligned.
    const int scol = (ln >> 2) * 64 + (ln & 3) * 16 + 12;

    // x prefetch (distance 1): xn = fp32 for step t+1, xf = bf16 frags for t
    f32x4 xn[8];
    bf16x8 xf[4];
    {
        #pragma unroll
        for (int c = 0; c < 4; ++c) {
            xn[2 * c]     = *(const f32x4*)(xrow + c * 32);
            xn[2 * c + 1] = *(const f32x4*)(xrow + c * 32 + 4);
        }
        #pragma unroll
        for (int c = 0; c < 4; ++c) {
            bf16x8 f;
            #pragma unroll
            for (int j = 0; j < 4; ++j) {
                f[j]     = (__bf16)xn[2 * c][j];
                f[j + 4] = (__bf16)xn[2 * c + 1][j];
            }
            xf[c] = f;
        }
    }

    float hm0 = 0.f, hm1 = 0.f, hm2 = 0.f, hm3 = 0.f;  // fp32 master h

    for (int t = 0; t < T_; ++t) {
        // issue x loads for t+1 NOW (fly during poll + compute)
        {
            const int tn = (t + 1 < T_) ? t + 1 : T_ - 1;
            const float* xp = xrow + (size_t)tn * D_;
            #pragma unroll
            for (int c = 0; c < 4; ++c) {
                xn[2 * c]     = *(const f32x4*)(xp + c * 32);
                xn[2 * c + 1] = *(const f32x4*)(xp + c * 32 + 4);
            }
        }

        f32x4 acc[8];
        #pragma unroll
        for (int i = 0; i < 8; ++i) acc[i] = (f32x4){0.f, 0.f, 0.f, 0.f};

        // x-projection MFMAs first: independent of the exchange.
        #pragma unroll
        for (int c = 0; c < 4; ++c)
            acc[c] = __builtin_amdgcn_mfma_f32_16x16x32_bf16(win[c], xf[c], acc[c], 0, 0, 0);

        if (t > 0) {
            const unsigned long long want1 =
                (unsigned long long)((((t - 1) >> 2) & 1) ^ 1) * 0x100000001ull;
            const int sb = (t - 1) & 1;
            const size_t slotoff =
                (size_t)((t - 1) & (RING_ - 1)) * (B_ * H_) + (size_t)b0 * H_;
            Pack16 pk[8];

            if (votefast && t >= TWARM_) {
                // ---- phase 1: sentinel poll on ring A (8B/lane) ----
                {
                    const unsigned long long* sp = (const unsigned long long*)
                        (h_exA + slotoff + 15 * H_ + scol);
                    int spins = 0;
                    for (;;) {
                        unsigned long long s;
                        asm volatile("global_load_dwordx2 %0, %1, off sc0 nt"
                                     : "=v"(s) : "v"(sp) : "memory");
                        asm volatile("s_waitcnt vmcnt(0)" : "+v"(s) :: "memory");
                        if (__all(((s ^ want1) & 0x100000001ull) == 0)) break;
                        if (((++spins) & 255) == 0 &&
                            __builtin_amdgcn_s_memrealtime() > tdead) break;
                    }
                }
                // ---- phase 2: one-shot 32KB fetch + per-word tag verify ----
                {
                    int spins = 0;
                    for (;;) {
                        #pragma unroll
                        for (int i = 0; i < 8; ++i) {
                            const int p = wv * 512 + i * 64 + ln;   // 16B piece
                            const __bf16* gp = h_exA + slotoff
                                + (size_t)(p >> 7) * H_ + (p & 127) * 8;
                            asm volatile("global_load_dwordx4 %0, %1, off sc0 nt"
                                         : "=v"(pk[i].d) : "v"(gp) : "memory");
                        }
                        asm volatile("s_waitcnt vmcnt(0)"
                                     : "+v"(pk[0].d), "+v"(pk[1].d), "+v"(pk[2].d),
                                       "+v"(pk[3].d), "+v"(pk[4].d), "+v"(pk[5].d),
                                       "+v"(pk[6].d), "+v"(pk[7].d) :: "memory");
                        __builtin_amdgcn_sched_barrier(0);
                        unsigned ok = 1u;
                        #pragma unroll
                        for (int i = 0; i < 8; ++i) {
                            ok &= (unsigned)(((pk[i].u[0] ^ want1) & 0x100000001ull) == 0);
                            ok &= (unsigned)(((pk[i].u[1] ^ want1) & 0x100000001ull) == 0);
                        }
                        if (__all(ok != 0u)) break;
                        if (((++spins) & 63) == 0 &&
                            __builtin_amdgcn_s_memrealtime() > tdead) break;  // anti-hang
                    }
                }
            } else {
                // ---- warmup / no-vote: ring B full poll (R6-proven) ----
                const __bf16* hbase = h_exB + slotoff;
                int spins = 0;
                for (;;) {
                    #pragma unroll
                    for (int i = 0; i < 8; ++i) {
                        const int p = wv * 512 + i * 64 + ln;
                        const unsigned long long* gp = (const unsigned long long*)
                            (hbase + (size_t)(p >> 7) * H_ + (p & 127) * 8);
                        pk[i].u[0] = __hip_atomic_load(gp, __ATOMIC_RELAXED,
                                                       __HIP_MEMORY_SCOPE_AGENT);
                        pk[i].u[1] = __hip_atomic_load(gp + 1, __ATOMIC_RELAXED,
                                                       __HIP_MEMORY_SCOPE_AGENT);
                    }
                    unsigned ok = 1u;
                    #pragma unroll
                    for (int i = 0; i < 8; ++i) {
                        ok &= (unsigned)(((pk[i].u[0] ^ want1) & 0x100000001ull) == 0);
                        ok &= (unsigned)(((pk[i].u[1] ^ want1) & 0x100000001ull) == 0);
                    }
                    if (__all(ok != 0u)) break;
                    __builtin_amdgcn_s_sleep(1);
                    if (((++spins) & 63) == 0 &&
                        __builtin_amdgcn_s_memrealtime() > tdead) break;  // anti-hang
                }
            }

            // ---- stage the loaded quarter into LDS, XOR swizzle ----
            #pragma unroll
            for (int i = 0; i < 8; ++i) {
                const int p = wv * 512 + i * 64 + ln;
                const int r = p >> 7, ch = p & 127;
                ls[sb][r][ch ^ (r & 7)] = pk[i].v;
            }

            __syncthreads();

            // ---- recurrent MFMAs from LDS, 8 accumulator chains ----
            #pragma unroll
            for (int kc = 0; kc < 32; ++kc) {
                bf16x8 a = ls[sb][nn][(kc * 4 + q) ^ (nn & 7)];
                acc[kc & 7] = __builtin_amdgcn_mfma_f32_16x16x32_bf16(wr[kc], a, acc[kc & 7], 0, 0, 0);
            }
        }

        const f32x4 asum = ((acc[0] + acc[4]) + (acc[1] + acc[5]))
                         + ((acc[2] + acc[6]) + (acc[3] + acc[7]));
        const float th0 = tanh_fast(asum[0]);
        const float th1 = tanh_fast(asum[1]);
        const float th2 = tanh_fast(asum[2]);
        const float th3 = tanh_fast(asum[3]);
        if (t == 0) {           // reference: h = tanh(xw[:,0]), no leak at t=0
            hm0 = th0; hm1 = th1; hm2 = th2; hm3 = th3;
        } else {                // h = 0.1*h + 0.9*tanh(.)
            hm0 = 0.1f * hm0 + 0.9f * th0;
            hm1 = 0.1f * hm1 + 0.9f * th1;
            hm2 = 0.1f * hm2 + 0.9f * th2;
            hm3 = 0.1f * hm3 + 0.9f * th3;
        }

        // publish 8B slice, lap tag in bit 0 of BOTH dwords — fire and forget.
        // Steady state: ring A ONLY (sc0 write-back L2 — no DRAM drain).
        {
            Pack8 p;
            p.v = (bf16x4){(__bf16)hm0, (__bf16)hm1, (__bf16)hm2, (__bf16)hm3};
            const unsigned long long tg =
                (unsigned long long)(((t >> 2) & 1) ^ 1) * 0x100000001ull;
            p.u = (p.u & ~0x100000001ull) | tg;
            const size_t poff = (size_t)(t & (RING_ - 1)) * (B_ * H_)
                                + hrow + n0 + q * 4;
            if (votefast) {
                unsigned long long* opA = (unsigned long long*)(h_exA + poff);
                asm volatile("global_store_dwordx2 %0, %1, off sc0"
                             :: "v"(opA), "v"(p.u) : "memory");
                if (t < TWARM_) {
                    unsigned long long* opB = (unsigned long long*)(h_exB + poff);
                    __hip_atomic_store(opB, p.u, __ATOMIC_RELAXED,
                                       __HIP_MEMORY_SCOPE_AGENT);
                }
            } else {
                unsigned long long* opB = (unsigned long long*)(h_exB + poff);
                __hip_atomic_store(opB, p.u, __ATOMIC_RELAXED,
                                   __HIP_MEMORY_SCOPE_AGENT);
            }
        }

        // off the critical path: tail collection + x bf16 conversion for t+1
        if (t >= T_ - LAST_) {
            f32x4* sp = (f32x4*)(hs + (size_t)(t - (T_ - LAST_)) * (B_ * H_)
                                    + hrow + n0 + q * 4);
            *sp = (f32x4){hm0, hm1, hm2, hm3};
        }
        #pragma unroll
        for (int c = 0; c < 4; ++c) {
            bf16x8 f;
            #pragma unroll
            for (int j = 0; j < 4; ++j) {
                f[j]     = (__bf16)xn[2 * c][j];
                f[j + 4] = (__bf16)xn[2 * c + 1][j];
            }
            xf[c] = f;
        }
    }

    // signal heaters: this worker is done
    if (tid == 0)
        __hip_atomic_fetch_add(flags + 200, 1, __ATOMIC_RELAXED,
                               __HIP_MEMORY_SCOPE_AGENT);
}

// Readout: out[b,:] = cat(hs)[b,:] @ W + bias.  One block per batch row.
__global__ __launch_bounds__(256) void esn_out(
    const float* __restrict__ hs, const float* __restrict__ Wm,
    const float* __restrict__ bias, float* __restrict__ out)
{
    const int b   = (int)blockIdx.x;
    const int tid = (int)threadIdx.x;
    float acc[O_];
    #pragma unroll
    for (int o = 0; o < O_; ++o) acc[o] = 0.f;

    for (int k = tid; k < LAST_ * H_; k += 256) {
        // cat order: k = t'*H + c  <->  hs[t'][b][c]
        const float hv = hs[(size_t)(k >> 10) * (B_ * H_) + (size_t)b * H_ + (k & (H_ - 1))];
        const f32x4* wp = (const f32x4*)(Wm + (size_t)k * O_);
        #pragma unroll
        for (int v = 0; v < 8; ++v) {
            f32x4 w4 = wp[v];
            acc[4 * v + 0] = fmaf(hv, w4[0], acc[4 * v + 0]);
            acc[4 * v + 1] = fmaf(hv, w4[1], acc[4 * v + 1]);
            acc[4 * v + 2] = fmaf(hv, w4[2], acc[4 * v + 2]);
            acc[4 * v + 3] = fmaf(hv, w4[3], acc[4 * v + 3]);
        }
    }

    __shared__ float red[256][O_ + 1];  // +1 pad: conflict-free column sums
    #pragma unroll
    for (int o = 0; o < O_; ++o) red[tid][o] = acc[o];
    __syncthreads();
    if (tid < O_) {
        float s = bias[tid];
        for (int i = 0; i < 256; ++i) s += red[i][tid];
        out[(size_t)b * O_ + tid] = s;
    }
}

extern "C" void kernel_launch(void* const* d_in, const int* in_sizes, int n_in,
                              void* d_out, int out_size, void* d_ws, size_t ws_size,
                              hipStream_t stream)
{
    const float* x    = (const float*)d_in[0];  // [128,2048,128]
    const float* w_in = (const float*)d_in[1];  // [128,1024]
    const float* w_r  = (const float*)d_in[2];  // [1024,1024]
    const float* Wm   = (const float*)d_in[3];  // [20480,32]
    const float* bias = (const float*)d_in[4];  // [32]
    float* out        = (float*)d_out;          // [128,32]

    const size_t flag_bytes = 4096;                                      // votes + done ctr
    const size_t ring_bytes = (size_t)RING_ * B_ * H_ * sizeof(__bf16);  // 1 MiB each
    const size_t hs_bytes   = (size_t)LAST_ * B_ * H_ * sizeof(float);   // 10 MiB
    if (ws_size < flag_bytes + 2 * ring_bytes + hs_bytes) return;  // fail loud

    int*    flags = (int*)d_ws;
    __bf16* h_exA = (__bf16*)((char*)d_ws + flag_bytes);
    __bf16* h_exB = (__bf16*)((char*)d_ws + flag_bytes + ring_bytes);
    float*  hs    = (float*)((char*)d_ws + flag_bytes + 2 * ring_bytes);

    // flags = 0 (no XCD votes yet; 0 fails the 0x5A5A pattern check; done ctr 0).
    // Rings = 0xAA: tag bit 0 = 0 = stale for t=0 (t=0 publishes tag 1).
    hipMemsetAsync(flags, 0x00, flag_bytes, stream);
    hipMemsetAsync(h_exA, 0xAA, 2 * ring_bytes, stream);

    hipLaunchKernelGGL(esn_persist, dim3(NB_ * NC_ + NHEAT_), dim3(256), 0, stream,
                       x, w_in, w_r, h_exA, h_exB, hs, flags);
    hipLaunchKernelGGL(esn_out, dim3(B_), dim3(256), 0, stream,
                       hs, Wm, bias, out);
}